// Round 8
// baseline (208.729 us; speedup 1.0000x reference)
//
#include <hip/hip_runtime.h>
#include <math.h>

#define LATENT   1024
#define WORD     64
#define NB_WORD  8192
#define BATCH    2048
#define NROWS    (BATCH * LATENT / WORD)   // 32768
#define NELEM    (BATCH * LATENT)          // 2097152

#define NCHUNK   8
#define CWCHUNK  (NB_WORD / NCHUNK)        // 1024
#define TPC      (CWCHUNK / 16)            // 64 tiles per chunk
#define NTILE    (NB_WORD / 16)            // 512 tiles
#define PKTS     (NTILE * 6 * 64)          // 196608 16B packets

typedef __attribute__((ext_vector_type(8))) __bf16 bf16x8;
typedef __attribute__((ext_vector_type(4))) float  f32x4;

// ---------------- kernel 1: e2[m] = sum_k emb[m][k]^2 (r1-proven) -----
__global__ __launch_bounds__(256) void vq_e2_kernel(
    const float* __restrict__ emb, float* __restrict__ e2) {
    int m = blockIdx.x * 256 + threadIdx.x;
    if (m >= NB_WORD) return;
    const float4* ep = reinterpret_cast<const float4*>(emb + (size_t)m * WORD);
    float s0 = 0.f, s1 = 0.f, s2 = 0.f, s3 = 0.f;
#pragma unroll
    for (int i = 0; i < 16; ++i) {
        float4 v = ep[i];
        s0 = fmaf(v.x, v.x, s0);
        s1 = fmaf(v.y, v.y, s1);
        s2 = fmaf(v.z, v.z, s2);
        s3 = fmaf(v.w, v.w, s3);
    }
    e2[m] = (s0 + s1) + (s2 + s3);
}

// ---------------- kernel 1b: pack e-splits in MFMA fragment order -----
// packet p = (tile*6 + spl*2 + Ks)*64 + lane ; 16 bytes = 8 bf16 of split
// level spl for (cw = tile*16 + (lane&15), k = Ks*32 + (lane>>4)*8 + e).
__global__ __launch_bounds__(256) void vq_epack_kernel(
    const float* __restrict__ emb, bf16x8* __restrict__ epack) {
    int p = blockIdx.x * 256 + threadIdx.x;    // 0..196607
    int lane = p & 63;
    int q    = p >> 6;
    int Ks   = q & 1;
    int r    = q >> 1;
    int spl  = r % 3;
    int tile = r / 3;
    int cw = tile * 16 + (lane & 15);
    int k0 = Ks * 32 + (lane >> 4) * 8;
    const float4* s4 = reinterpret_cast<const float4*>(emb + (size_t)cw * WORD + k0);
    float4 a = s4[0], b = s4[1];
    float tv[8] = {a.x, a.y, a.z, a.w, b.x, b.y, b.z, b.w};
    bf16x8 o;
#pragma unroll
    for (int e = 0; e < 8; ++e) {
        float v = tv[e];
        __bf16 h  = (__bf16)v;
        float r1  = v - (float)h;
        __bf16 m  = (__bf16)r1;
        float r2  = r1 - (float)m;
        __bf16 lo = (__bf16)r2;
        o[e] = (spl == 0) ? h : ((spl == 1) ? m : lo);
    }
    epack[p] = o;
}

__device__ __forceinline__ void gload_lds16(const char* g, char* l) {
    __builtin_amdgcn_global_load_lds(
        (const __attribute__((address_space(1))) void*)g,
        (__attribute__((address_space(3))) void*)l, 16, 0, 0);
}

// ---------------- kernel 2: MFMA split-bf16 argmin --------------------
// 256 thr = 4 waves; block = 128 rows x 1024-cw chunk; wave = 32 rows.
// 2-phase schedule, raw barrier (no vmcnt(0)+lgkmcnt(0) compiler drain at
// the barrier): drain own DMA(t) -> s_barrier -> issue DMA(t+1) -> compute.
__global__ __launch_bounds__(256)
__attribute__((amdgpu_waves_per_eu(4, 8)))
void vq_argmin_kernel(
    const float* __restrict__ z, const bf16x8* __restrict__ epack,
    const float* __restrict__ e2, unsigned long long* __restrict__ best) {

    __shared__ __align__(16) char le[2 * 6144];

    const int tid   = threadIdx.x;
    const int lane  = tid & 63;
    const int wband = tid >> 6;               // 0..3
    const int l15   = lane & 15;
    const int l4    = lane >> 4;              // 0..3
    const int rowbase   = blockIdx.x * 128 + wband * 32;
    const int tile0     = blockIdx.y * TPC;
    const int chunkbase = blockIdx.y * CWCHUNK;
    const float* e2g    = e2 + chunkbase;

    // ---- build A-frags (z 3-way bf16 split) in registers ----
    bf16x8 A[2][2][3];                         // [mt][Ks][spl]
    const float4* zf4 = reinterpret_cast<const float4*>(z);
#pragma unroll
    for (int mt = 0; mt < 2; ++mt) {
        int row = rowbase + mt * 16 + l15;
#pragma unroll
        for (int Ks = 0; Ks < 2; ++Ks) {
            float4 v0 = zf4[(size_t)row * 16 + Ks * 8 + l4 * 2];
            float4 v1 = zf4[(size_t)row * 16 + Ks * 8 + l4 * 2 + 1];
            float tv[8] = {v0.x, v0.y, v0.z, v0.w, v1.x, v1.y, v1.z, v1.w};
#pragma unroll
            for (int e = 0; e < 8; ++e) {
                float v = tv[e];
                __bf16 h  = (__bf16)v;
                float r1  = v - (float)h;
                __bf16 m  = (__bf16)r1;
                float r2  = r1 - (float)m;
                __bf16 lo = (__bf16)r2;
                A[mt][Ks][0][e] = h;
                A[mt][Ks][1][e] = m;
                A[mt][Ks][2][e] = lo;
            }
        }
    }

    // ---- issue DMA for tile 0 into buf 0 (drained at iter-0 vmcnt) ----
    {
        const char* src = (const char*)epack + (size_t)tile0 * 6144;
        gload_lds16(src + wband * 1024 + lane * 16, le + wband * 1024);
        if (wband < 2)
            gload_lds16(src + (4 + wband) * 1024 + lane * 16,
                        le + (4 + wband) * 1024);
    }

    float bestd[8] = {INFINITY, INFINITY, INFINITY, INFINITY,
                      INFINITY, INFINITY, INFINITY, INFINITY};
    int   bt[8]    = {0, 0, 0, 0, 0, 0, 0, 0};

    for (int t = 0; t < TPC; ++t) {
        const int buf = t & 1;
        float e2v = e2g[t * 16 + l15];         // L1-resident (32 KB total)

        // drain own DMA(t) + e2v, then raw barrier (prefetch for t+1 is
        // issued AFTER the barrier, so nothing live is drained here).
        asm volatile("s_waitcnt vmcnt(0)" ::: "memory");
        __builtin_amdgcn_sched_barrier(0);
        __builtin_amdgcn_s_barrier();          // all waves' DMA(t) complete

        // ---- issue DMA(t+1) into buf^1 (crosses the next barrier) ----
        {
            const int tn = (t + 1 < TPC) ? (t + 1) : t;   // last: harmless reload
            const char* src = (const char*)epack + (size_t)(tile0 + tn) * 6144;
            char* dst = le + (buf ^ 1) * 6144;
            gload_lds16(src + wband * 1024 + lane * 16, dst + wband * 1024);
            if (wband < 2)
                gload_lds16(src + (4 + wband) * 1024 + lane * 16,
                            dst + (4 + wband) * 1024);
        }

        // ---- compute on buf ----
        f32x4 acc0 = {0.f, 0.f, 0.f, 0.f};
        f32x4 acc1 = {0.f, 0.f, 0.f, 0.f};
        __builtin_amdgcn_s_setprio(1);
#pragma unroll
        for (int Ks = 0; Ks < 2; ++Ks) {
            const char* bbase = le + buf * 6144 + (size_t)Ks * 1024 + lane * 16;
            bf16x8 Bh = *reinterpret_cast<const bf16x8*>(bbase);          // spl0
            bf16x8 Bm = *reinterpret_cast<const bf16x8*>(bbase + 2048);   // spl1
            bf16x8 Bl = *reinterpret_cast<const bf16x8*>(bbase + 4096);   // spl2
            // combos: hh, mh, lh, hm, mm, hl  (x 2 row-tiles)
            acc0 = __builtin_amdgcn_mfma_f32_16x16x32_bf16(A[0][Ks][0], Bh, acc0, 0, 0, 0);
            acc1 = __builtin_amdgcn_mfma_f32_16x16x32_bf16(A[1][Ks][0], Bh, acc1, 0, 0, 0);
            acc0 = __builtin_amdgcn_mfma_f32_16x16x32_bf16(A[0][Ks][1], Bh, acc0, 0, 0, 0);
            acc1 = __builtin_amdgcn_mfma_f32_16x16x32_bf16(A[1][Ks][1], Bh, acc1, 0, 0, 0);
            acc0 = __builtin_amdgcn_mfma_f32_16x16x32_bf16(A[0][Ks][2], Bh, acc0, 0, 0, 0);
            acc1 = __builtin_amdgcn_mfma_f32_16x16x32_bf16(A[1][Ks][2], Bh, acc1, 0, 0, 0);
            acc0 = __builtin_amdgcn_mfma_f32_16x16x32_bf16(A[0][Ks][0], Bm, acc0, 0, 0, 0);
            acc1 = __builtin_amdgcn_mfma_f32_16x16x32_bf16(A[1][Ks][0], Bm, acc1, 0, 0, 0);
            acc0 = __builtin_amdgcn_mfma_f32_16x16x32_bf16(A[0][Ks][1], Bm, acc0, 0, 0, 0);
            acc1 = __builtin_amdgcn_mfma_f32_16x16x32_bf16(A[1][Ks][1], Bm, acc1, 0, 0, 0);
            acc0 = __builtin_amdgcn_mfma_f32_16x16x32_bf16(A[0][Ks][0], Bl, acc0, 0, 0, 0);
            acc1 = __builtin_amdgcn_mfma_f32_16x16x32_bf16(A[1][Ks][0], Bl, acc1, 0, 0, 0);
        }
        __builtin_amdgcn_s_setprio(0);

        // ---- fold: score = e2 - 2*dot (z2 is row-constant, dropped) ----
#pragma unroll
        for (int v = 0; v < 4; ++v) {
            float d0 = fmaf(-2.0f, acc0[v], e2v);
            if (d0 < bestd[v])     { bestd[v]     = d0; bt[v]     = t; }
            float d1 = fmaf(-2.0f, acc1[v], e2v);
            if (d1 < bestd[4 + v]) { bestd[4 + v] = d1; bt[4 + v] = t; }
        }
    }

    // ---- cross-lane min over the 16 cw-lanes, then atomicMin merge ----
#pragma unroll
    for (int mt = 0; mt < 2; ++mt) {
#pragma unroll
        for (int v = 0; v < 4; ++v) {
            float bd = bestd[mt * 4 + v];
            int   cw = chunkbase + bt[mt * 4 + v] * 16 + l15;
            unsigned db = __float_as_uint(bd);
            db = (db & 0x80000000u) ? ~db : (db | 0x80000000u);
            unsigned long long key =
                ((unsigned long long)db << 32) | (unsigned)cw;
#pragma unroll
            for (int off = 1; off < 16; off <<= 1) {
                unsigned long long o = __shfl_xor(key, off);
                key = (o < key) ? o : key;
            }
            if (l15 == 0)
                atomicMin(&best[rowbase + mt * 16 + l4 * 4 + v], key);
        }
    }
}

// ---------------- kernel 3: gather + straight-through output + loss ---
__global__ __launch_bounds__(256) void vq_out_kernel(
    const float* __restrict__ z, const float* __restrict__ emb,
    const unsigned long long* __restrict__ best,
    float* __restrict__ out, float* __restrict__ lsum) {
    const int base = (blockIdx.x * 256 + threadIdx.x) * 8;
    const int row  = base >> 6;
    const int m    = (int)(best[row] & 0xFFFFFFFFull);

    const float4* zp = reinterpret_cast<const float4*>(z + base);
    const float4* qp = reinterpret_cast<const float4*>(emb + (size_t)m * WORD + (base & 63));
    float4* op = reinterpret_cast<float4*>(out + base);

    float s = 0.f;
#pragma unroll
    for (int i = 0; i < 2; ++i) {
        float4 zv = zp[i];
        float4 qv = qp[i];
        float dx = qv.x - zv.x, dy = qv.y - zv.y, dz = qv.z - zv.z, dw = qv.w - zv.w;
        float4 ov;
        ov.x = zv.x + dx; ov.y = zv.y + dy; ov.z = zv.z + dz; ov.w = zv.w + dw;
        op[i] = ov;
        s += dx*dx + dy*dy + dz*dz + dw*dw;
    }

#pragma unroll
    for (int off = 32; off > 0; off >>= 1) s += __shfl_down(s, off);
    __shared__ float wsum[4];
    int lane = threadIdx.x & 63, wid = threadIdx.x >> 6;
    if (lane == 0) wsum[wid] = s;
    __syncthreads();
    if (threadIdx.x == 0)
        atomicAdd(lsum, (wsum[0] + wsum[1]) + (wsum[2] + wsum[3]));
}

// ---------------- kernel 4: finalize loss -----------------------------
__global__ void vq_loss_kernel(const float* __restrict__ lsum,
                               float* __restrict__ loss_out) {
    float mean = lsum[0] * (1.0f / (float)NELEM);
    loss_out[0] = mean + 2.5f * mean;
}

extern "C" void kernel_launch(void* const* d_in, const int* in_sizes, int n_in,
                              void* d_out, int out_size, void* d_ws, size_t ws_size,
                              hipStream_t stream) {
    const float* z   = (const float*)d_in[0];   // z_mean (2048,1024)
    // d_in[1] = z_log_var, unused by the reference
    const float* emb = (const float*)d_in[2];   // (8192,64)
    float* out = (float*)d_out;                 // [z_q_st flat (2097152), loss]

    // ws layout: epack 3 MB | e2 32 KB | best 256 KB | lsum 4 B
    bf16x8* epack = (bf16x8*)d_ws;
    float*  e2    = (float*)((char*)d_ws + (size_t)PKTS * 16);
    unsigned long long* best =
        (unsigned long long*)((char*)e2 + NB_WORD * sizeof(float));
    float* lsum = (float*)((char*)best + NROWS * sizeof(unsigned long long));

    hipMemsetAsync(best, 0xFF, NROWS * sizeof(unsigned long long), stream);
    hipMemsetAsync(lsum, 0, sizeof(float), stream);

    vq_e2_kernel<<<NB_WORD / 256, 256, 0, stream>>>(emb, e2);
    vq_epack_kernel<<<PKTS / 256, 256, 0, stream>>>(emb, epack);
    vq_argmin_kernel<<<dim3(NROWS / 128, NCHUNK), 256, 0, stream>>>(
        z, epack, e2, best);
    vq_out_kernel<<<NELEM / (256 * 8), 256, 0, stream>>>(z, emb, best, out, lsum);
    vq_loss_kernel<<<1, 1, 0, stream>>>(lsum, out + NELEM);
}

// Round 9
// 194.605 us; speedup vs baseline: 1.0726x; 1.0726x over previous
//
#include <hip/hip_runtime.h>
#include <math.h>

#define LATENT   1024
#define WORD     64
#define NB_WORD  8192
#define BATCH    2048
#define NROWS    (BATCH * LATENT / WORD)   // 32768
#define NELEM    (BATCH * LATENT)          // 2097152

#define NCHUNK   8
#define CWCHUNK  (NB_WORD / NCHUNK)        // 1024
#define TPC      (CWCHUNK / 16)            // 64 tiles per chunk
#define NTILE    (NB_WORD / 16)            // 512 tiles
#define PKTS     (NTILE * 6 * 64)          // 196608 16B packets

typedef __attribute__((ext_vector_type(8))) __bf16 bf16x8;
typedef __attribute__((ext_vector_type(4))) float  f32x4;

// ---------------- kernel 1: e2[m] = sum_k emb[m][k]^2 (r1-proven) -----
__global__ __launch_bounds__(256) void vq_e2_kernel(
    const float* __restrict__ emb, float* __restrict__ e2) {
    int m = blockIdx.x * 256 + threadIdx.x;
    if (m >= NB_WORD) return;
    const float4* ep = reinterpret_cast<const float4*>(emb + (size_t)m * WORD);
    float s0 = 0.f, s1 = 0.f, s2 = 0.f, s3 = 0.f;
#pragma unroll
    for (int i = 0; i < 16; ++i) {
        float4 v = ep[i];
        s0 = fmaf(v.x, v.x, s0);
        s1 = fmaf(v.y, v.y, s1);
        s2 = fmaf(v.z, v.z, s2);
        s3 = fmaf(v.w, v.w, s3);
    }
    e2[m] = (s0 + s1) + (s2 + s3);
}

// ---------------- kernel 1b: pack e-splits in MFMA fragment order -----
// packet p = (tile*6 + spl*2 + Ks)*64 + lane ; 16 bytes = 8 bf16 of split
// level spl for (cw = tile*16 + (lane&15), k = Ks*32 + (lane>>4)*8 + e).
__global__ __launch_bounds__(256) void vq_epack_kernel(
    const float* __restrict__ emb, bf16x8* __restrict__ epack) {
    int p = blockIdx.x * 256 + threadIdx.x;    // 0..196607
    int lane = p & 63;
    int q    = p >> 6;
    int Ks   = q & 1;
    int r    = q >> 1;
    int spl  = r % 3;
    int tile = r / 3;
    int cw = tile * 16 + (lane & 15);
    int k0 = Ks * 32 + (lane >> 4) * 8;
    const float4* s4 = reinterpret_cast<const float4*>(emb + (size_t)cw * WORD + k0);
    float4 a = s4[0], b = s4[1];
    float tv[8] = {a.x, a.y, a.z, a.w, b.x, b.y, b.z, b.w};
    bf16x8 o;
#pragma unroll
    for (int e = 0; e < 8; ++e) {
        float v = tv[e];
        __bf16 h  = (__bf16)v;
        float r1  = v - (float)h;
        __bf16 m  = (__bf16)r1;
        float r2  = r1 - (float)m;
        __bf16 lo = (__bf16)r2;
        o[e] = (spl == 0) ? h : ((spl == 1) ? m : lo);
    }
    epack[p] = o;
}

__device__ __forceinline__ void gload_lds16(const char* g, char* l) {
    __builtin_amdgcn_global_load_lds(
        (const __attribute__((address_space(1))) void*)g,
        (__attribute__((address_space(3))) void*)l, 16, 0, 0);
}

// ---------------- kernel 2: MFMA split-bf16 argmin --------------------
// 256 thr = 4 waves; block = 128 rows x 1024-cw chunk; wave = 32 rows.
// 2-phase raw-barrier schedule (r8-verified) + r9 additions:
//   - e2 prefetched one tile ahead in a register (no L2 latency at drain)
//   - tile-offset stagger per block (L2 line/channel spread)
//   - s_sleep phase stagger (decorrelate MFMA bursts across blocks)
__global__ __launch_bounds__(256)
__attribute__((amdgpu_waves_per_eu(4, 8)))
void vq_argmin_kernel(
    const float* __restrict__ z, const bf16x8* __restrict__ epack,
    const float* __restrict__ e2, unsigned long long* __restrict__ best) {

    // phase stagger: rounds are equal-length, so initial offsets persist
    {
        int ph = blockIdx.x & 3;
        if (ph == 1) __builtin_amdgcn_s_sleep(2);
        else if (ph == 2) __builtin_amdgcn_s_sleep(4);
        else if (ph == 3) __builtin_amdgcn_s_sleep(6);
    }

    __shared__ __align__(16) char le[2 * 6144];

    const int tid   = threadIdx.x;
    const int lane  = tid & 63;
    const int wband = tid >> 6;               // 0..3
    const int l15   = lane & 15;
    const int l4    = lane >> 4;              // 0..3
    const int rowbase   = blockIdx.x * 128 + wband * 32;
    const int tile0     = blockIdx.y * TPC;
    const int chunkbase = blockIdx.y * CWCHUNK;
    const float* e2g    = e2 + chunkbase;
    const int off       = (blockIdx.x & 15) * 4;   // tile start offset

    // ---- build A-frags (z 3-way bf16 split) in registers ----
    bf16x8 A[2][2][3];                         // [mt][Ks][spl]
    const float4* zf4 = reinterpret_cast<const float4*>(z);
#pragma unroll
    for (int mt = 0; mt < 2; ++mt) {
        int row = rowbase + mt * 16 + l15;
#pragma unroll
        for (int Ks = 0; Ks < 2; ++Ks) {
            float4 v0 = zf4[(size_t)row * 16 + Ks * 8 + l4 * 2];
            float4 v1 = zf4[(size_t)row * 16 + Ks * 8 + l4 * 2 + 1];
            float tv[8] = {v0.x, v0.y, v0.z, v0.w, v1.x, v1.y, v1.z, v1.w};
#pragma unroll
            for (int e = 0; e < 8; ++e) {
                float v = tv[e];
                __bf16 h  = (__bf16)v;
                float r1  = v - (float)h;
                __bf16 m  = (__bf16)r1;
                float r2  = r1 - (float)m;
                __bf16 lo = (__bf16)r2;
                A[mt][Ks][0][e] = h;
                A[mt][Ks][1][e] = m;
                A[mt][Ks][2][e] = lo;
            }
        }
    }

    // ---- issue DMA for tile 'off' into buf 0; prefetch its e2 ----
    {
        const char* src = (const char*)epack + (size_t)(tile0 + off) * 6144;
        gload_lds16(src + wband * 1024 + lane * 16, le + wband * 1024);
        if (wband < 2)
            gload_lds16(src + (4 + wband) * 1024 + lane * 16,
                        le + (4 + wband) * 1024);
    }
    float e2next = e2g[off * 16 + l15];

    float bestd[8] = {INFINITY, INFINITY, INFINITY, INFINITY,
                      INFINITY, INFINITY, INFINITY, INFINITY};
    int   bt[8]    = {0, 0, 0, 0, 0, 0, 0, 0};

    for (int tt = 0; tt < TPC; ++tt) {
        const int buf = tt & 1;
        const int t   = (tt + off) & (TPC - 1);       // actual tile index

        // drain own DMA(t) + e2(t) (both issued a full tile ago), then raw
        // barrier (prefetches for t+1 are issued AFTER the barrier).
        asm volatile("s_waitcnt vmcnt(0)" ::: "memory");
        __builtin_amdgcn_sched_barrier(0);
        __builtin_amdgcn_s_barrier();          // all waves' DMA(t) complete

        const float e2v = e2next;              // value landed last iteration

        // ---- issue DMA(t+1) into buf^1 + e2 prefetch (cross barrier) ----
        {
            const int tn = (tt + 1 + off) & (TPC - 1);  // wraps: harmless reload
            const char* src = (const char*)epack + (size_t)(tile0 + tn) * 6144;
            char* dst = le + (buf ^ 1) * 6144;
            gload_lds16(src + wband * 1024 + lane * 16, dst + wband * 1024);
            if (wband < 2)
                gload_lds16(src + (4 + wband) * 1024 + lane * 16,
                            dst + (4 + wband) * 1024);
            e2next = e2g[tn * 16 + l15];
        }

        // ---- compute on buf ----
        f32x4 acc0 = {0.f, 0.f, 0.f, 0.f};
        f32x4 acc1 = {0.f, 0.f, 0.f, 0.f};
        __builtin_amdgcn_s_setprio(1);
#pragma unroll
        for (int Ks = 0; Ks < 2; ++Ks) {
            const char* bbase = le + buf * 6144 + (size_t)Ks * 1024 + lane * 16;
            bf16x8 Bh = *reinterpret_cast<const bf16x8*>(bbase);          // spl0
            bf16x8 Bm = *reinterpret_cast<const bf16x8*>(bbase + 2048);   // spl1
            bf16x8 Bl = *reinterpret_cast<const bf16x8*>(bbase + 4096);   // spl2
            // combos: hh, mh, lh, hm, mm, hl  (x 2 row-tiles)
            acc0 = __builtin_amdgcn_mfma_f32_16x16x32_bf16(A[0][Ks][0], Bh, acc0, 0, 0, 0);
            acc1 = __builtin_amdgcn_mfma_f32_16x16x32_bf16(A[1][Ks][0], Bh, acc1, 0, 0, 0);
            acc0 = __builtin_amdgcn_mfma_f32_16x16x32_bf16(A[0][Ks][1], Bh, acc0, 0, 0, 0);
            acc1 = __builtin_amdgcn_mfma_f32_16x16x32_bf16(A[1][Ks][1], Bh, acc1, 0, 0, 0);
            acc0 = __builtin_amdgcn_mfma_f32_16x16x32_bf16(A[0][Ks][2], Bh, acc0, 0, 0, 0);
            acc1 = __builtin_amdgcn_mfma_f32_16x16x32_bf16(A[1][Ks][2], Bh, acc1, 0, 0, 0);
            acc0 = __builtin_amdgcn_mfma_f32_16x16x32_bf16(A[0][Ks][0], Bm, acc0, 0, 0, 0);
            acc1 = __builtin_amdgcn_mfma_f32_16x16x32_bf16(A[1][Ks][0], Bm, acc1, 0, 0, 0);
            acc0 = __builtin_amdgcn_mfma_f32_16x16x32_bf16(A[0][Ks][1], Bm, acc0, 0, 0, 0);
            acc1 = __builtin_amdgcn_mfma_f32_16x16x32_bf16(A[1][Ks][1], Bm, acc1, 0, 0, 0);
            acc0 = __builtin_amdgcn_mfma_f32_16x16x32_bf16(A[0][Ks][0], Bl, acc0, 0, 0, 0);
            acc1 = __builtin_amdgcn_mfma_f32_16x16x32_bf16(A[1][Ks][0], Bl, acc1, 0, 0, 0);
        }
        __builtin_amdgcn_s_setprio(0);

        // ---- fold: score = e2 - 2*dot (z2 is row-constant, dropped) ----
#pragma unroll
        for (int v = 0; v < 4; ++v) {
            float d0 = fmaf(-2.0f, acc0[v], e2v);
            if (d0 < bestd[v])     { bestd[v]     = d0; bt[v]     = t; }
            float d1 = fmaf(-2.0f, acc1[v], e2v);
            if (d1 < bestd[4 + v]) { bestd[4 + v] = d1; bt[4 + v] = t; }
        }
    }

    // ---- cross-lane min over the 16 cw-lanes, then atomicMin merge ----
    // (u64 pack: min dist, tie -> min cw == first occurrence; visit-order
    //  independent, so the tile-offset stagger is safe.)
#pragma unroll
    for (int mt = 0; mt < 2; ++mt) {
#pragma unroll
        for (int v = 0; v < 4; ++v) {
            float bd = bestd[mt * 4 + v];
            int   cw = chunkbase + bt[mt * 4 + v] * 16 + l15;
            unsigned db = __float_as_uint(bd);
            db = (db & 0x80000000u) ? ~db : (db | 0x80000000u);
            unsigned long long key =
                ((unsigned long long)db << 32) | (unsigned)cw;
#pragma unroll
            for (int off2 = 1; off2 < 16; off2 <<= 1) {
                unsigned long long o = __shfl_xor(key, off2);
                key = (o < key) ? o : key;
            }
            if (l15 == 0)
                atomicMin(&best[rowbase + mt * 16 + l4 * 4 + v], key);
        }
    }
}

// ---------------- kernel 3: gather + straight-through output + loss ---
__global__ __launch_bounds__(256) void vq_out_kernel(
    const float* __restrict__ z, const float* __restrict__ emb,
    const unsigned long long* __restrict__ best,
    float* __restrict__ out, float* __restrict__ lsum) {
    const int base = (blockIdx.x * 256 + threadIdx.x) * 8;
    const int row  = base >> 6;
    const int m    = (int)(best[row] & 0xFFFFFFFFull);

    const float4* zp = reinterpret_cast<const float4*>(z + base);
    const float4* qp = reinterpret_cast<const float4*>(emb + (size_t)m * WORD + (base & 63));
    float4* op = reinterpret_cast<float4*>(out + base);

    float s = 0.f;
#pragma unroll
    for (int i = 0; i < 2; ++i) {
        float4 zv = zp[i];
        float4 qv = qp[i];
        float dx = qv.x - zv.x, dy = qv.y - zv.y, dz = qv.z - zv.z, dw = qv.w - zv.w;
        float4 ov;
        ov.x = zv.x + dx; ov.y = zv.y + dy; ov.z = zv.z + dz; ov.w = zv.w + dw;
        op[i] = ov;
        s += dx*dx + dy*dy + dz*dz + dw*dw;
    }

#pragma unroll
    for (int off = 32; off > 0; off >>= 1) s += __shfl_down(s, off);
    __shared__ float wsum[4];
    int lane = threadIdx.x & 63, wid = threadIdx.x >> 6;
    if (lane == 0) wsum[wid] = s;
    __syncthreads();
    if (threadIdx.x == 0)
        atomicAdd(lsum, (wsum[0] + wsum[1]) + (wsum[2] + wsum[3]));
}

// ---------------- kernel 4: finalize loss -----------------------------
__global__ void vq_loss_kernel(const float* __restrict__ lsum,
                               float* __restrict__ loss_out) {
    float mean = lsum[0] * (1.0f / (float)NELEM);
    loss_out[0] = mean + 2.5f * mean;
}

extern "C" void kernel_launch(void* const* d_in, const int* in_sizes, int n_in,
                              void* d_out, int out_size, void* d_ws, size_t ws_size,
                              hipStream_t stream) {
    const float* z   = (const float*)d_in[0];   // z_mean (2048,1024)
    // d_in[1] = z_log_var, unused by the reference
    const float* emb = (const float*)d_in[2];   // (8192,64)
    float* out = (float*)d_out;                 // [z_q_st flat (2097152), loss]

    // ws layout: epack 3 MB | e2 32 KB | best 256 KB | lsum 4 B
    bf16x8* epack = (bf16x8*)d_ws;
    float*  e2    = (float*)((char*)d_ws + (size_t)PKTS * 16);
    unsigned long long* best =
        (unsigned long long*)((char*)e2 + NB_WORD * sizeof(float));
    float* lsum = (float*)((char*)best + NROWS * sizeof(unsigned long long));

    hipMemsetAsync(best, 0xFF, NROWS * sizeof(unsigned long long), stream);
    hipMemsetAsync(lsum, 0, sizeof(float), stream);

    vq_e2_kernel<<<NB_WORD / 256, 256, 0, stream>>>(emb, e2);
    vq_epack_kernel<<<PKTS / 256, 256, 0, stream>>>(emb, epack);
    vq_argmin_kernel<<<dim3(NROWS / 128, NCHUNK), 256, 0, stream>>>(
        z, epack, e2, best);
    vq_out_kernel<<<NELEM / (256 * 8), 256, 0, stream>>>(z, emb, best, out, lsum);
    vq_loss_kernel<<<1, 1, 0, stream>>>(lsum, out + NELEM);
}

// Round 10
// 189.560 us; speedup vs baseline: 1.1011x; 1.0266x over previous
//
#include <hip/hip_runtime.h>
#include <math.h>

#define LATENT   1024
#define WORD     64
#define NB_WORD  8192
#define BATCH    2048
#define NROWS    (BATCH * LATENT / WORD)   // 32768
#define NELEM    (BATCH * LATENT)          // 2097152

#define NCHUNK   8
#define CWCHUNK  (NB_WORD / NCHUNK)        // 1024
#define TPC      (CWCHUNK / 16)            // 64 tiles per chunk
#define NTILE    (NB_WORD / 16)            // 512 tiles
#define PKTS     (NTILE * 6 * 64)          // 196608 16B packets

typedef __attribute__((ext_vector_type(8))) __bf16 bf16x8;
typedef __attribute__((ext_vector_type(4))) float  f32x4;

// ------- kernel 1: fused e2 + epack (one emb read, r1 e2 chain order) -
// thread m owns codeword m: e2[m] = sum k&3-lane chains (bit-identical to
// r1); packets p=(tile*6+spl*2+Ks)*64 + q*16 + (m&15) hold 8 bf16 of split
// level spl for k = Ks*32 + q*8 + e.
__global__ __launch_bounds__(256) void vq_prep_kernel(
    const float* __restrict__ emb, float* __restrict__ e2,
    bf16x8* __restrict__ epack) {
    int m = blockIdx.x * 256 + threadIdx.x;
    int tile = m >> 4, l15 = m & 15;
    float s0 = 0.f, s1 = 0.f, s2 = 0.f, s3 = 0.f;
#pragma unroll
    for (int Ks = 0; Ks < 2; ++Ks) {
#pragma unroll
        for (int q = 0; q < 4; ++q) {
            const float4* s4 = reinterpret_cast<const float4*>(
                emb + (size_t)m * WORD + Ks * 32 + q * 8);
            float4 a = s4[0], b = s4[1];
            float tv[8] = {a.x, a.y, a.z, a.w, b.x, b.y, b.z, b.w};
            bf16x8 oh, om, ol;
#pragma unroll
            for (int e = 0; e < 8; ++e) {
                float v = tv[e];
                // e2 partial chains (same order as r1: s_{k&3}, k ascending)
                if ((e & 3) == 0) s0 = fmaf(v, v, s0);
                else if ((e & 3) == 1) s1 = fmaf(v, v, s1);
                else if ((e & 3) == 2) s2 = fmaf(v, v, s2);
                else s3 = fmaf(v, v, s3);
                __bf16 h  = (__bf16)v;
                float r1  = v - (float)h;
                __bf16 mm = (__bf16)r1;
                float r2  = r1 - (float)mm;
                __bf16 lo = (__bf16)r2;
                oh[e] = h; om[e] = mm; ol[e] = lo;
            }
            size_t base = ((size_t)tile * 6) * 64 + q * 16 + l15;
            epack[base + (size_t)(0 * 2 + Ks) * 64] = oh;
            epack[base + (size_t)(1 * 2 + Ks) * 64] = om;
            epack[base + (size_t)(2 * 2 + Ks) * 64] = ol;
        }
    }
    e2[m] = (s0 + s1) + (s2 + s3);
}

__device__ __forceinline__ void gload_lds16(const char* g, char* l) {
    __builtin_amdgcn_global_load_lds(
        (const __attribute__((address_space(1))) void*)g,
        (__attribute__((address_space(3))) void*)l, 16, 0, 0);
}

// ---------------- kernel 2: MFMA split-bf16 argmin --------------------
// 256 thr = 4 waves; block = 128 rows x 1024-cw chunk; wave = 32 rows.
// r9 2-phase raw-barrier schedule + r10 delayed fold: fold(phase t-1)
// executes inside phase t's ds_read latency window; only the last fold
// is exposed (epilogue). First fold is a no-op via e2prev=+INF.
__global__ __launch_bounds__(256)
__attribute__((amdgpu_waves_per_eu(4, 8)))
void vq_argmin_kernel(
    const float* __restrict__ z, const bf16x8* __restrict__ epack,
    const float* __restrict__ e2, unsigned long long* __restrict__ best) {

    // phase stagger: rounds are equal-length, so initial offsets persist
    {
        int ph = blockIdx.x & 3;
        if (ph == 1) __builtin_amdgcn_s_sleep(2);
        else if (ph == 2) __builtin_amdgcn_s_sleep(4);
        else if (ph == 3) __builtin_amdgcn_s_sleep(6);
    }

    __shared__ __align__(16) char le[2 * 6144];

    const int tid   = threadIdx.x;
    const int lane  = tid & 63;
    const int wband = tid >> 6;               // 0..3
    const int l15   = lane & 15;
    const int l4    = lane >> 4;              // 0..3
    const int rowbase   = blockIdx.x * 128 + wband * 32;
    const int tile0     = blockIdx.y * TPC;
    const int chunkbase = blockIdx.y * CWCHUNK;
    const float* e2g    = e2 + chunkbase;
    const int off       = (blockIdx.x & 15) * 4;   // tile start offset

    // ---- build A-frags (z 3-way bf16 split) in registers ----
    bf16x8 A[2][2][3];                         // [mt][Ks][spl]
    const float4* zf4 = reinterpret_cast<const float4*>(z);
#pragma unroll
    for (int mt = 0; mt < 2; ++mt) {
        int row = rowbase + mt * 16 + l15;
#pragma unroll
        for (int Ks = 0; Ks < 2; ++Ks) {
            float4 v0 = zf4[(size_t)row * 16 + Ks * 8 + l4 * 2];
            float4 v1 = zf4[(size_t)row * 16 + Ks * 8 + l4 * 2 + 1];
            float tv[8] = {v0.x, v0.y, v0.z, v0.w, v1.x, v1.y, v1.z, v1.w};
#pragma unroll
            for (int e = 0; e < 8; ++e) {
                float v = tv[e];
                __bf16 h  = (__bf16)v;
                float r1  = v - (float)h;
                __bf16 m  = (__bf16)r1;
                float r2  = r1 - (float)m;
                __bf16 lo = (__bf16)r2;
                A[mt][Ks][0][e] = h;
                A[mt][Ks][1][e] = m;
                A[mt][Ks][2][e] = lo;
            }
        }
    }

    // ---- issue DMA for tile 'off' into buf 0; prefetch its e2 ----
    {
        const char* src = (const char*)epack + (size_t)(tile0 + off) * 6144;
        gload_lds16(src + wband * 1024 + lane * 16, le + wband * 1024);
        if (wband < 2)
            gload_lds16(src + (4 + wband) * 1024 + lane * 16,
                        le + (4 + wband) * 1024);
    }
    float e2next = e2g[off * 16 + l15];

    float bestd[8] = {INFINITY, INFINITY, INFINITY, INFINITY,
                      INFINITY, INFINITY, INFINITY, INFINITY};
    int   bt[8]    = {0, 0, 0, 0, 0, 0, 0, 0};

    // delayed-fold state: previous phase's accs (first fold is a no-op:
    // fmaf(-2, 0, +INF) = +INF, never < bestd)
    f32x4 pacc0 = {0.f, 0.f, 0.f, 0.f};
    f32x4 pacc1 = {0.f, 0.f, 0.f, 0.f};
    float e2prev = INFINITY;
    int   tprev  = 0;

    for (int tt = 0; tt < TPC; ++tt) {
        const int buf = tt & 1;
        const int t   = (tt + off) & (TPC - 1);       // actual tile index

        // drain own DMA(t) + e2(t) (issued a full phase ago), raw barrier
        asm volatile("s_waitcnt vmcnt(0)" ::: "memory");
        __builtin_amdgcn_sched_barrier(0);
        __builtin_amdgcn_s_barrier();          // all waves' DMA(t) complete

        const float e2v = e2next;              // landed last phase

        // ---- issue DMA(t+1) into buf^1 + e2 prefetch (cross barrier) ----
        {
            const int tn = (tt + 1 + off) & (TPC - 1);  // wrap: harmless reload
            const char* src = (const char*)epack + (size_t)(tile0 + tn) * 6144;
            char* dst = le + (buf ^ 1) * 6144;
            gload_lds16(src + wband * 1024 + lane * 16, dst + wband * 1024);
            if (wband < 2)
                gload_lds16(src + (4 + wband) * 1024 + lane * 16,
                            dst + (4 + wband) * 1024);
            e2next = e2g[tn * 16 + l15];
        }

        // ---- issue all 6 B-frag reads (latency hidden by fold below) ----
        const char* b0 = le + buf * 6144 + lane * 16;
        bf16x8 Bh0 = *reinterpret_cast<const bf16x8*>(b0);
        bf16x8 Bm0 = *reinterpret_cast<const bf16x8*>(b0 + 2048);
        bf16x8 Bl0 = *reinterpret_cast<const bf16x8*>(b0 + 4096);
        bf16x8 Bh1 = *reinterpret_cast<const bf16x8*>(b0 + 1024);
        bf16x8 Bm1 = *reinterpret_cast<const bf16x8*>(b0 + 3072);
        bf16x8 Bl1 = *reinterpret_cast<const bf16x8*>(b0 + 5120);

        // ---- fold PREVIOUS phase (independent of the reads above) ----
#pragma unroll
        for (int v = 0; v < 4; ++v) {
            float d0 = fmaf(-2.0f, pacc0[v], e2prev);
            if (d0 < bestd[v])     { bestd[v]     = d0; bt[v]     = tprev; }
            float d1 = fmaf(-2.0f, pacc1[v], e2prev);
            if (d1 < bestd[4 + v]) { bestd[4 + v] = d1; bt[4 + v] = tprev; }
        }

        // ---- compute on buf ----
        f32x4 acc0 = {0.f, 0.f, 0.f, 0.f};
        f32x4 acc1 = {0.f, 0.f, 0.f, 0.f};
        __builtin_amdgcn_s_setprio(1);
        // combos: hh, mh, lh, hm, mm, hl  (x 2 row-tiles), Ks=0 then Ks=1
        acc0 = __builtin_amdgcn_mfma_f32_16x16x32_bf16(A[0][0][0], Bh0, acc0, 0, 0, 0);
        acc1 = __builtin_amdgcn_mfma_f32_16x16x32_bf16(A[1][0][0], Bh0, acc1, 0, 0, 0);
        acc0 = __builtin_amdgcn_mfma_f32_16x16x32_bf16(A[0][0][1], Bh0, acc0, 0, 0, 0);
        acc1 = __builtin_amdgcn_mfma_f32_16x16x32_bf16(A[1][0][1], Bh0, acc1, 0, 0, 0);
        acc0 = __builtin_amdgcn_mfma_f32_16x16x32_bf16(A[0][0][2], Bh0, acc0, 0, 0, 0);
        acc1 = __builtin_amdgcn_mfma_f32_16x16x32_bf16(A[1][0][2], Bh0, acc1, 0, 0, 0);
        acc0 = __builtin_amdgcn_mfma_f32_16x16x32_bf16(A[0][0][0], Bm0, acc0, 0, 0, 0);
        acc1 = __builtin_amdgcn_mfma_f32_16x16x32_bf16(A[1][0][0], Bm0, acc1, 0, 0, 0);
        acc0 = __builtin_amdgcn_mfma_f32_16x16x32_bf16(A[0][0][1], Bm0, acc0, 0, 0, 0);
        acc1 = __builtin_amdgcn_mfma_f32_16x16x32_bf16(A[1][0][1], Bm0, acc1, 0, 0, 0);
        acc0 = __builtin_amdgcn_mfma_f32_16x16x32_bf16(A[0][0][0], Bl0, acc0, 0, 0, 0);
        acc1 = __builtin_amdgcn_mfma_f32_16x16x32_bf16(A[1][0][0], Bl0, acc1, 0, 0, 0);
        acc0 = __builtin_amdgcn_mfma_f32_16x16x32_bf16(A[0][1][0], Bh1, acc0, 0, 0, 0);
        acc1 = __builtin_amdgcn_mfma_f32_16x16x32_bf16(A[1][1][0], Bh1, acc1, 0, 0, 0);
        acc0 = __builtin_amdgcn_mfma_f32_16x16x32_bf16(A[0][1][1], Bh1, acc0, 0, 0, 0);
        acc1 = __builtin_amdgcn_mfma_f32_16x16x32_bf16(A[1][1][1], Bh1, acc1, 0, 0, 0);
        acc0 = __builtin_amdgcn_mfma_f32_16x16x32_bf16(A[0][1][2], Bh1, acc0, 0, 0, 0);
        acc1 = __builtin_amdgcn_mfma_f32_16x16x32_bf16(A[1][1][2], Bh1, acc1, 0, 0, 0);
        acc0 = __builtin_amdgcn_mfma_f32_16x16x32_bf16(A[0][1][0], Bm1, acc0, 0, 0, 0);
        acc1 = __builtin_amdgcn_mfma_f32_16x16x32_bf16(A[1][1][0], Bm1, acc1, 0, 0, 0);
        acc0 = __builtin_amdgcn_mfma_f32_16x16x32_bf16(A[0][1][1], Bm1, acc0, 0, 0, 0);
        acc1 = __builtin_amdgcn_mfma_f32_16x16x32_bf16(A[1][1][1], Bm1, acc1, 0, 0, 0);
        acc0 = __builtin_amdgcn_mfma_f32_16x16x32_bf16(A[0][1][0], Bl1, acc0, 0, 0, 0);
        acc1 = __builtin_amdgcn_mfma_f32_16x16x32_bf16(A[1][1][0], Bl1, acc1, 0, 0, 0);
        __builtin_amdgcn_s_setprio(0);

        // ---- hand off to next phase's fold ----
        pacc0 = acc0; pacc1 = acc1; e2prev = e2v; tprev = t;
    }

    // ---- epilogue: fold the last phase ----
#pragma unroll
    for (int v = 0; v < 4; ++v) {
        float d0 = fmaf(-2.0f, pacc0[v], e2prev);
        if (d0 < bestd[v])     { bestd[v]     = d0; bt[v]     = tprev; }
        float d1 = fmaf(-2.0f, pacc1[v], e2prev);
        if (d1 < bestd[4 + v]) { bestd[4 + v] = d1; bt[4 + v] = tprev; }
    }

    // ---- cross-lane min over the 16 cw-lanes, then atomicMin merge ----
    // (u64 pack: min dist, tie -> min cw == first occurrence; visit-order
    //  independent, so the tile-offset stagger is safe.)
#pragma unroll
    for (int mt = 0; mt < 2; ++mt) {
#pragma unroll
        for (int v = 0; v < 4; ++v) {
            float bd = bestd[mt * 4 + v];
            int   cw = chunkbase + bt[mt * 4 + v] * 16 + l15;
            unsigned db = __float_as_uint(bd);
            db = (db & 0x80000000u) ? ~db : (db | 0x80000000u);
            unsigned long long key =
                ((unsigned long long)db << 32) | (unsigned)cw;
#pragma unroll
            for (int off2 = 1; off2 < 16; off2 <<= 1) {
                unsigned long long o = __shfl_xor(key, off2);
                key = (o < key) ? o : key;
            }
            if (l15 == 0)
                atomicMin(&best[rowbase + mt * 16 + l4 * 4 + v], key);
        }
    }
}

// ---------------- kernel 3: gather + straight-through output + loss ---
__global__ __launch_bounds__(256) void vq_out_kernel(
    const float* __restrict__ z, const float* __restrict__ emb,
    const unsigned long long* __restrict__ best,
    float* __restrict__ out, float* __restrict__ lsum) {
    const int base = (blockIdx.x * 256 + threadIdx.x) * 8;
    const int row  = base >> 6;
    const int m    = (int)(best[row] & 0xFFFFFFFFull);

    const float4* zp = reinterpret_cast<const float4*>(z + base);
    const float4* qp = reinterpret_cast<const float4*>(emb + (size_t)m * WORD + (base & 63));
    float4* op = reinterpret_cast<float4*>(out + base);

    float s = 0.f;
#pragma unroll
    for (int i = 0; i < 2; ++i) {
        float4 zv = zp[i];
        float4 qv = qp[i];
        float dx = qv.x - zv.x, dy = qv.y - zv.y, dz = qv.z - zv.z, dw = qv.w - zv.w;
        float4 ov;
        ov.x = zv.x + dx; ov.y = zv.y + dy; ov.z = zv.z + dz; ov.w = zv.w + dw;
        op[i] = ov;
        s += dx*dx + dy*dy + dz*dz + dw*dw;
    }

#pragma unroll
    for (int off = 32; off > 0; off >>= 1) s += __shfl_down(s, off);
    __shared__ float wsum[4];
    int lane = threadIdx.x & 63, wid = threadIdx.x >> 6;
    if (lane == 0) wsum[wid] = s;
    __syncthreads();
    if (threadIdx.x == 0)
        atomicAdd(lsum, (wsum[0] + wsum[1]) + (wsum[2] + wsum[3]));
}

// ---------------- kernel 4: finalize loss -----------------------------
__global__ void vq_loss_kernel(const float* __restrict__ lsum,
                               float* __restrict__ loss_out) {
    float mean = lsum[0] * (1.0f / (float)NELEM);
    loss_out[0] = mean + 2.5f * mean;
}

extern "C" void kernel_launch(void* const* d_in, const int* in_sizes, int n_in,
                              void* d_out, int out_size, void* d_ws, size_t ws_size,
                              hipStream_t stream) {
    const float* z   = (const float*)d_in[0];   // z_mean (2048,1024)
    // d_in[1] = z_log_var, unused by the reference
    const float* emb = (const float*)d_in[2];   // (8192,64)
    float* out = (float*)d_out;                 // [z_q_st flat (2097152), loss]

    // ws layout: epack 3 MB | e2 32 KB | best 256 KB | lsum 4 B
    bf16x8* epack = (bf16x8*)d_ws;
    float*  e2    = (float*)((char*)d_ws + (size_t)PKTS * 16);
    unsigned long long* best =
        (unsigned long long*)((char*)e2 + NB_WORD * sizeof(float));
    float* lsum = (float*)((char*)best + NROWS * sizeof(unsigned long long));

    hipMemsetAsync(best, 0xFF, NROWS * sizeof(unsigned long long), stream);
    hipMemsetAsync(lsum, 0, sizeof(float), stream);

    vq_prep_kernel<<<NB_WORD / 256, 256, 0, stream>>>(emb, e2, epack);
    vq_argmin_kernel<<<dim3(NROWS / 128, NCHUNK), 256, 0, stream>>>(
        z, epack, e2, best);
    vq_out_kernel<<<NELEM / (256 * 8), 256, 0, stream>>>(z, emb, best, out, lsum);
    vq_loss_kernel<<<1, 1, 0, stream>>>(lsum, out + NELEM);
}